// Round 11
// baseline (156.229 us; speedup 1.0000x reference)
//
#include <hip/hip_runtime.h>
#include <cstdint>

#define KDIM 128
#define BATCH 131072

typedef __attribute__((ext_vector_type(8))) short short8x;          // MFMA A/B frag
typedef __attribute__((ext_vector_type(4))) float float4x;          // MFMA C/D frag
typedef __attribute__((ext_vector_type(4))) unsigned int uint4x;

// pack two fp32 -> bf16x2 dword, round-half-up (1 add per elem + 1 v_perm)
__device__ __forceinline__ unsigned int pk_bf16(float a, float b) {
    unsigned int ua = __float_as_uint(a) + 0x8000u;
    unsigned int ub = __float_as_uint(b) + 0x8000u;
    return __builtin_amdgcn_perm(ub, ua, 0x07060302u);  // {hi16(b), hi16(a)}
}

__device__ __forceinline__ unsigned short f2bf(float f) {   // RNE, prep kernel only
    unsigned int u = __float_as_uint(f);
    u += 0x7FFFu + ((u >> 16) & 1u);
    return (unsigned short)(u >> 16);
}

// clamped Pade tanh: err<=0.025 abs; y-sensitivity 0.05 -> <1.3e-3 in y. No transcendental.
__device__ __forceinline__ float tanh_pade(float v) {
    float z  = fminf(fmaxf(v, -4.0f), 4.0f);
    float z2 = z * z;
    float num = z * (27.0f + z2);
    float den = fmaf(z2, 9.0f, 27.0f);
    return num * __frcp_rn(den);
}

// Repack W[k][n] fp32 -> fragment-lane-major bf16: coalesced reads, scattered writes.
// Main kernel reads Wf[((nt*4+ks)*64 + lane)*8 + j] = W[ks*32+(lane>>4)*8+j][nt*16+(lane&15)]
__global__ void prep_weights(const float* __restrict__ W1, const float* __restrict__ W2,
                             unsigned short* __restrict__ W1f, unsigned short* __restrict__ W2f) {
    int idx = blockIdx.x * 256 + threadIdx.x;   // 0..16383, coalesced read W[idx]
    int k = idx >> 7, n = idx & 127;
    int ks = k >> 5, j = k & 7;
    int lane = ((k >> 3) & 3) * 16 + (n & 15);
    int nt = n >> 4;
    int dst = ((nt * 4 + ks) * 64 + lane) * 8 + j;
    W1f[dst] = f2bf(W1[idx]);
    W2f[dst] = f2bf(W2[idx]);
}

// Register-direct structure (r10 lesson: the in-order vmcnt queue makes any
// global_load_lds staging serialize a full-tile HBM drain into every wave's chain).
//  - x frag loads: direct to VGPR, NO manual waitcnt -- compiler emits per-use
//    counted waits, so mm1 starts on the first arrivals and the rest pipeline.
//  - epilogue x: 8-instr L2-hot re-load in (nt,quad) layout (r0: duplicate read
//    is absorbed by L2/L3).
//  - LDS only for y-staging (8KB/wave): swizzled write -> linear read -> 1KB
//    coalesced stores (r2-verified, WRITE-ideal).
//  - lb(256,4): 32KB/block -> 4 blocks/CU, 16 waves/CU, VGPR cap 128 (body ~110).
__global__ __launch_bounds__(256, 4) void koopman_main(
        const float* __restrict__ x, const float* __restrict__ b1,
        const float* __restrict__ b2, const unsigned short* __restrict__ W1f,
        const unsigned short* __restrict__ W2f, float* __restrict__ y) {
    __shared__ __align__(16) float Yst[4][2048];   // y-staging only: 8KB/wave

    const int tid  = threadIdx.x;
    const int lane = tid & 63;
    const int wave = tid >> 6;
    const int l15  = lane & 15;
    const int quad = lane >> 4;
    const int Lx   = l15 + ((lane & 16) << 1);   // shuffle src: l15 + 32a
    const bool bhi = (lane & 32) != 0;
    const int row0 = blockIdx.x * 64 + wave * 16;

    float* Yw = Yst[wave];
    const float* xrow = x + (size_t)(row0 + l15) * KDIM;

    // ---- x frag loads direct to VGPR + pack (x fp32 dies immediately) ----
    short8x xf[4];
    #pragma unroll
    for (int ks = 0; ks < 4; ++ks) {
        float4 v0 = *(const float4*)(xrow + quad * 8 + ks * 32);
        float4 v1 = *(const float4*)(xrow + quad * 8 + ks * 32 + 4);
        uint4x u;
        u[0] = pk_bf16(v0.x, v0.y);
        u[1] = pk_bf16(v0.z, v0.w);
        u[2] = pk_bf16(v1.x, v1.y);
        u[3] = pk_bf16(v1.z, v1.w);
        xf[ks] = __builtin_bit_cast(short8x, u);
    }

    // ---- matmul 1: D[col][row] = W1^T @ X^T (W loads compiler-pipelined) ----
    float4x acc[8];
    #pragma unroll
    for (int nt = 0; nt < 8; ++nt) acc[nt] = (float4x){0.f, 0.f, 0.f, 0.f};
    #pragma unroll
    for (int ks = 0; ks < 4; ++ks)
        #pragma unroll
        for (int nt = 0; nt < 8; ++nt) {
            short8x w = *(const short8x*)&W1f[((nt * 4 + ks) * 64 + lane) * 8];
            acc[nt] = __builtin_amdgcn_mfma_f32_16x16x32_bf16(w, xf[ks], acc[nt], 0, 0, 0);
        }

    // ---- bias + tanh -> packed bf16 pairs in registers:
    //      lane(l15,q) holds d[nt] = H[l15][16nt+4q + {0,1 | 2,3}] ----
    uint2 d[8];
    #pragma unroll
    for (int nt = 0; nt < 8; ++nt) {
        float4 bb = *(const float4*)&b1[nt * 16 + quad * 4];
        float4x v = acc[nt];
        d[nt].x = pk_bf16(tanh_pade(v[0] + bb.x), tanh_pade(v[1] + bb.y));
        d[nt].y = pk_bf16(tanh_pade(v[2] + bb.z), tanh_pade(v[3] + bb.w));
    }

    // ---- matmul 2: B-frags via quad shuffles (r3-verified mapping) ----
    float4x acc2[8];
    #pragma unroll
    for (int nt = 0; nt < 8; ++nt) acc2[nt] = (float4x){0.f, 0.f, 0.f, 0.f};
    #pragma unroll
    for (int ks = 0; ks < 4; ++ks) {
        uint2 lo = d[2 * ks], hi = d[2 * ks + 1];
        unsigned s0 = (unsigned)__shfl((int)lo.x, Lx);
        unsigned s1 = (unsigned)__shfl((int)lo.y, Lx);
        unsigned s2 = (unsigned)__shfl((int)lo.x, Lx + 16);
        unsigned s3 = (unsigned)__shfl((int)lo.y, Lx + 16);
        unsigned t0 = (unsigned)__shfl((int)hi.x, Lx);
        unsigned t1 = (unsigned)__shfl((int)hi.y, Lx);
        unsigned t2 = (unsigned)__shfl((int)hi.x, Lx + 16);
        unsigned t3 = (unsigned)__shfl((int)hi.y, Lx + 16);
        uint4x u;
        u[0] = bhi ? t0 : s0;
        u[1] = bhi ? t1 : s1;
        u[2] = bhi ? t2 : s2;
        u[3] = bhi ? t3 : s3;
        short8x hf = __builtin_bit_cast(short8x, u);
        #pragma unroll
        for (int nt = 0; nt < 8; ++nt) {
            short8x w = *(const short8x*)&W2f[((nt * 4 + ks) * 64 + lane) * 8];
            acc2[nt] = __builtin_amdgcn_mfma_f32_16x16x32_bf16(w, hf, acc2[nt], 0, 0, 0);
        }
    }

    // ---- fused epilogue: x re-loaded L2-hot in (nt,quad) layout; out -> LDS swizzled ----
    #pragma unroll
    for (int nt = 0; nt < 8; ++nt) {
        float4 bv = *(const float4*)&b2[nt * 16 + quad * 4];
        float4 xv = *(const float4*)(xrow + nt * 16 + quad * 4);
        float4x v = acc2[nt];
        float4 out;
        {
            float tm = 0.01f * (v[0] + bv.x);
            float tw = 0.01f * (v[1] + bv.y);
            float tm2 = tm * tm, tw2 = tw * tw;
            float ex = fmaf(tm2, fmaf(tm, 0.16666667f, 0.5f), 1.0f + tm);
            float s  = tw * fmaf(tw2, -0.16666667f, 1.0f);
            float c  = fmaf(tw2, -0.5f, 1.0f);
            out.x = ex * fmaf(c, xv.x, -s * xv.y);
            out.y = ex * fmaf(s, xv.x,  c * xv.y);
        }
        {
            float tm = 0.01f * (v[2] + bv.z);
            float tw = 0.01f * (v[3] + bv.w);
            float tm2 = tm * tm, tw2 = tw * tw;
            float ex = fmaf(tm2, fmaf(tm, 0.16666667f, 0.5f), 1.0f + tm);
            float s  = tw * fmaf(tw2, -0.16666667f, 1.0f);
            float c  = fmaf(tw2, -0.5f, 1.0f);
            out.z = ex * fmaf(c, xv.z, -s * xv.w);
            out.w = ex * fmaf(s, xv.z,  c * xv.w);
        }
        // slot (nt*4+quad)^(l15&7): 8 lanes per 4-bank group per instr = conflict-optimal
        *(float4*)&Yw[l15 * 128 + (((nt * 4 + quad) ^ (l15 & 7)) << 2)] = out;
    }

    // ---- y store: linear LDS read; global dst carries inverse swizzle (WRITE-ideal) ----
    #pragma unroll
    for (int c = 0; c < 8; ++c) {
        int r  = c * 2 + (lane >> 5);
        int sp = (lane & 31) ^ (r & 7);
        float4 v = *(const float4*)&Yw[c * 256 + lane * 4];
        *(float4*)(y + (size_t)(row0 + r) * KDIM + sp * 4) = v;
    }
}

extern "C" void kernel_launch(void* const* d_in, const int* in_sizes, int n_in,
                              void* d_out, int out_size, void* d_ws, size_t ws_size,
                              hipStream_t stream) {
    const float* x  = (const float*)d_in[0];
    const float* W1 = (const float*)d_in[1];
    const float* b1 = (const float*)d_in[2];
    const float* W2 = (const float*)d_in[3];
    const float* b2 = (const float*)d_in[4];
    float* y = (float*)d_out;

    unsigned short* W1f = (unsigned short*)d_ws;
    unsigned short* W2f = W1f + 128 * 128;

    prep_weights<<<64, 256, 0, stream>>>(W1, W2, W1f, W2f);
    koopman_main<<<BATCH / 64, 256, 0, stream>>>(x, b1, b2, W1f, W2f, y);
}

// Round 13
// 146.774 us; speedup vs baseline: 1.0644x; 1.0644x over previous
//
#include <hip/hip_runtime.h>
#include <cstdint>

#define KDIM 128
#define BATCH 131072

typedef __attribute__((ext_vector_type(8))) short short8x;          // MFMA A/B frag
typedef __attribute__((ext_vector_type(4))) float float4x;          // MFMA C/D frag
typedef __attribute__((ext_vector_type(4))) unsigned int uint4x;

// pack two fp32 -> bf16x2 dword, round-half-up (1 add per elem + 1 v_perm)
__device__ __forceinline__ unsigned int pk_bf16(float a, float b) {
    unsigned int ua = __float_as_uint(a) + 0x8000u;
    unsigned int ub = __float_as_uint(b) + 0x8000u;
    return __builtin_amdgcn_perm(ub, ua, 0x07060302u);  // {hi16(b), hi16(a)}
}

__device__ __forceinline__ unsigned short f2bf(float f) {   // RNE, prep kernel only
    unsigned int u = __float_as_uint(f);
    u += 0x7FFFu + ((u >> 16) & 1u);
    return (unsigned short)(u >> 16);
}

// clamped Pade tanh: err<=0.025 abs; y-sensitivity 0.05 -> <1.3e-3 in y. No transcendental.
__device__ __forceinline__ float tanh_pade(float v) {
    float z  = fminf(fmaxf(v, -4.0f), 4.0f);
    float z2 = z * z;
    float num = z * (27.0f + z2);
    float den = fmaf(z2, 9.0f, 27.0f);
    return num * __frcp_rn(den);
}

// direct-to-LDS 16B async copy: LDS dest = (wave-uniform base) + lane*16
__device__ __forceinline__ void gload_lds16(const void* g, void* l) {
    __builtin_amdgcn_global_load_lds(
        (const __attribute__((address_space(1))) void*)g,
        (__attribute__((address_space(3))) void*)l, 16, 0, 0);
}

// Repack W[k][n] fp32 -> fragment-lane-major bf16: coalesced reads, scattered writes.
// Main kernel reads Wf[((nt*4+ks)*64 + lane)*8 + j] = W[ks*32+(lane>>4)*8+j][nt*16+(lane&15)]
__global__ void prep_weights(const float* __restrict__ W1, const float* __restrict__ W2,
                             unsigned short* __restrict__ W1f, unsigned short* __restrict__ W2f) {
    int idx = blockIdx.x * 256 + threadIdx.x;   // 0..16383, coalesced read W[idx]
    int k = idx >> 7, n = idx & 127;
    int ks = k >> 5, j = k & 7;
    int lane = ((k >> 3) & 3) * 16 + (n & 15);
    int nt = n >> 4;
    int dst = ((nt * 4 + ks) * 64 + lane) * 8 + j;
    W1f[dst] = f2bf(W1[idx]);
    W2f[dst] = f2bf(W2[idx]);
}

// ALL-LINEAR global addressing experiment (r12): every global access -- x stage,
// W frags, y store -- is lane-linear (lane i -> base + i*16), zero permutation.
// LDS is plain row-major [16][128]; the 16-way frag-read conflicts this reintroduces
// were measured at ~0.6us total (r1 vs r2). W1-ks0 prefetched before the x-wait so
// W-loading overlaps the staging latency instead of being fenced behind it.
__global__ __launch_bounds__(256, 3) void koopman_main(
        const float* __restrict__ x, const float* __restrict__ b1,
        const float* __restrict__ b2, const unsigned short* __restrict__ W1f,
        const unsigned short* __restrict__ W2f, float* __restrict__ y) {
    __shared__ __align__(16) float XY[4][2048];   // 8KB/wave x/y stage, row-major linear

    const int tid  = threadIdx.x;
    const int lane = tid & 63;
    const int wave = tid >> 6;
    const int l15  = lane & 15;
    const int quad = lane >> 4;
    const int Lx   = l15 + ((lane & 16) << 1);   // shuffle src: l15 + 32a
    const bool bhi = (lane & 32) != 0;
    const int row0 = blockIdx.x * 64 + wave * 16;

    float* Xw = XY[wave];

    // ---- stage 16 rows x 512B of x: 8 x 1KB, source LINEAR (no permutation) ----
    #pragma unroll
    for (int c = 0; c < 8; ++c) {
        const float* src = x + (size_t)(row0 + c * 2 + (lane >> 5)) * KDIM + (lane & 31) * 4;
        gload_lds16(src, &Xw[c * 256]);   // Xw = row-major [16][128]
    }

    // ---- W1 ks0 prefetch: in flight concurrently with the x stage ----
    short8x wf0[8];
    #pragma unroll
    for (int nt = 0; nt < 8; ++nt)
        wf0[nt] = *(const short8x*)&W1f[((nt * 4 + 0) * 64 + lane) * 8];

    asm volatile("s_waitcnt vmcnt(0)" ::: "memory");

    // ---- pack bf16 B-frags (X^T): lane reads row l15 (16-way conflict, accepted) ----
    short8x xf[4];
    #pragma unroll
    for (int ks = 0; ks < 4; ++ks) {
        float4 v0 = *(const float4*)&Xw[l15 * 128 + ks * 32 + quad * 8];
        float4 v1 = *(const float4*)&Xw[l15 * 128 + ks * 32 + quad * 8 + 4];
        uint4x u;
        u[0] = pk_bf16(v0.x, v0.y);
        u[1] = pk_bf16(v0.z, v0.w);
        u[2] = pk_bf16(v1.x, v1.y);
        u[3] = pk_bf16(v1.z, v1.w);
        xf[ks] = __builtin_bit_cast(short8x, u);
    }

    // ---- matmul 1: ks0 from prefetched frags; W loads lane-linear 1KB each ----
    float4x acc[8];
    #pragma unroll
    for (int nt = 0; nt < 8; ++nt) acc[nt] = (float4x){0.f, 0.f, 0.f, 0.f};
    #pragma unroll
    for (int ks = 0; ks < 4; ++ks)
        #pragma unroll
        for (int nt = 0; nt < 8; ++nt) {
            short8x w = (ks == 0) ? wf0[nt]
                      : *(const short8x*)&W1f[((nt * 4 + ks) * 64 + lane) * 8];
            acc[nt] = __builtin_amdgcn_mfma_f32_16x16x32_bf16(w, xf[ks], acc[nt], 0, 0, 0);
        }

    // ---- bias + tanh -> packed bf16 pairs in registers ----
    uint2 d[8];
    #pragma unroll
    for (int nt = 0; nt < 8; ++nt) {
        float4 bb = *(const float4*)&b1[nt * 16 + quad * 4];
        float4x v = acc[nt];
        d[nt].x = pk_bf16(tanh_pade(v[0] + bb.x), tanh_pade(v[1] + bb.y));
        d[nt].y = pk_bf16(tanh_pade(v[2] + bb.z), tanh_pade(v[3] + bb.w));
    }

    // ---- matmul 2: B-frags via quad shuffles (r3-verified mapping) ----
    float4x acc2[8];
    #pragma unroll
    for (int nt = 0; nt < 8; ++nt) acc2[nt] = (float4x){0.f, 0.f, 0.f, 0.f};
    #pragma unroll
    for (int ks = 0; ks < 4; ++ks) {
        uint2 lo = d[2 * ks], hi = d[2 * ks + 1];
        unsigned s0 = (unsigned)__shfl((int)lo.x, Lx);
        unsigned s1 = (unsigned)__shfl((int)lo.y, Lx);
        unsigned s2 = (unsigned)__shfl((int)lo.x, Lx + 16);
        unsigned s3 = (unsigned)__shfl((int)lo.y, Lx + 16);
        unsigned t0 = (unsigned)__shfl((int)hi.x, Lx);
        unsigned t1 = (unsigned)__shfl((int)hi.y, Lx);
        unsigned t2 = (unsigned)__shfl((int)hi.x, Lx + 16);
        unsigned t3 = (unsigned)__shfl((int)hi.y, Lx + 16);
        uint4x u;
        u[0] = bhi ? t0 : s0;
        u[1] = bhi ? t1 : s1;
        u[2] = bhi ? t2 : s2;
        u[3] = bhi ? t3 : s3;
        short8x hf = __builtin_bit_cast(short8x, u);
        #pragma unroll
        for (int nt = 0; nt < 8; ++nt) {
            short8x w = *(const short8x*)&W2f[((nt * 4 + ks) * 64 + lane) * 8];
            acc2[nt] = __builtin_amdgcn_mfma_f32_16x16x32_bf16(w, hf, acc2[nt], 0, 0, 0);
        }
    }

    // ---- fused epilogue, in-place in LDS (linear slots; write conflicts accepted) ----
    #pragma unroll
    for (int nt = 0; nt < 8; ++nt) {
        float4 bv = *(const float4*)&b2[nt * 16 + quad * 4];
        int off = l15 * 128 + nt * 16 + quad * 4;
        float4 xv = *(const float4*)&Xw[off];
        float4x v = acc2[nt];
        float4 out;
        {
            float tm = 0.01f * (v[0] + bv.x);
            float tw = 0.01f * (v[1] + bv.y);
            float tm2 = tm * tm, tw2 = tw * tw;
            float ex = fmaf(tm2, fmaf(tm, 0.16666667f, 0.5f), 1.0f + tm);
            float s  = tw * fmaf(tw2, -0.16666667f, 1.0f);
            float c  = fmaf(tw2, -0.5f, 1.0f);
            out.x = ex * fmaf(c, xv.x, -s * xv.y);
            out.y = ex * fmaf(s, xv.x,  c * xv.y);
        }
        {
            float tm = 0.01f * (v[2] + bv.z);
            float tw = 0.01f * (v[3] + bv.w);
            float tm2 = tm * tm, tw2 = tw * tw;
            float ex = fmaf(tm2, fmaf(tm, 0.16666667f, 0.5f), 1.0f + tm);
            float s  = tw * fmaf(tw2, -0.16666667f, 1.0f);
            float c  = fmaf(tw2, -0.5f, 1.0f);
            out.z = ex * fmaf(c, xv.z, -s * xv.w);
            out.w = ex * fmaf(s, xv.z,  c * xv.w);
        }
        *(float4*)&Xw[off] = out;
    }

    // ---- y store: linear LDS read -> LINEAR global store (lane i -> base + i*16).
    //      First kernel in the session with textbook-optimal store addressing. ----
    #pragma unroll
    for (int c = 0; c < 8; ++c) {
        float4 v = *(const float4*)&Xw[c * 256 + lane * 4];
        float* dst = y + (size_t)(row0 + c * 2 + (lane >> 5)) * KDIM + (lane & 31) * 4;
        *(float4*)dst = v;
    }
}

extern "C" void kernel_launch(void* const* d_in, const int* in_sizes, int n_in,
                              void* d_out, int out_size, void* d_ws, size_t ws_size,
                              hipStream_t stream) {
    const float* x  = (const float*)d_in[0];
    const float* W1 = (const float*)d_in[1];
    const float* b1 = (const float*)d_in[2];
    const float* W2 = (const float*)d_in[3];
    const float* b2 = (const float*)d_in[4];
    float* y = (float*)d_out;

    unsigned short* W1f = (unsigned short*)d_ws;
    unsigned short* W2f = W1f + 128 * 128;

    prep_weights<<<64, 256, 0, stream>>>(W1, W2, W1f, W2f);
    koopman_main<<<BATCH / 64, 256, 0, stream>>>(x, b1, b2, W1f, W2f, y);
}